// Round 2
// baseline (2307.666 us; speedup 1.0000x reference)
//
#include <hip/hip_runtime.h>
#include <hip/hip_bf16.h>
#include <math.h>

// ---------------------------------------------------------------------------
// TransformerModel: 12-layer causal linear-attention encoder.
// B=1, S=1024, D_MODEL=512, H=8, Dh=64, FF=2048. All tensors fp32 (x int32).
// Round 11: GEMM path rewrite. R10 fixed attention; budget shows ~1000us in
// the 1-wave-per-tile gemm32 (direct-from-global, latency-bound, ~70TF).
// New gemm128: 128x128 block tile, 4 waves (64x64/wave, 4x4 frags), BK=64,
// double-buffered global_load_lds(16B) staging, 2-phase prefetch pipeline,
// XOR-swizzled LDS (pre-swizzled global source + swizzled ds_read_b128).
// Attention / LN / embed / transpose kernels unchanged (bisection).
// ---------------------------------------------------------------------------

#define S_LEN 1024
#define DM 512
#define NH 8
#define DH 64
#define DFF 2048
#define NLAYER 12
#define CHUNK 64
#define NCH (S_LEN / CHUNK)   // 16

#define ACT_NONE 0
#define ACT_PHI  1
#define ACT_GELU 2

typedef short s16x8 __attribute__((ext_vector_type(8)));
typedef float f32x4 __attribute__((ext_vector_type(4)));

__device__ __forceinline__ short f2bf(float x) {
    __hip_bfloat16 h = __float2bfloat16(x);
    return *reinterpret_cast<short*>(&h);
}

__device__ __forceinline__ void fma4(f32x4& a, float s, const f32x4 v) {
    a.x = fmaf(s, v.x, a.x); a.y = fmaf(s, v.y, a.y);
    a.z = fmaf(s, v.z, a.z); a.w = fmaf(s, v.w, a.w);
}

// ---------------- embedding gather (writes bf16) ----------------
__global__ __launch_bounds__(256) void embed_kernel(
    const int* __restrict__ x,
    const float* __restrict__ t0, const float* __restrict__ t1,
    const float* __restrict__ t2, const float* __restrict__ t3,
    const float* __restrict__ t4, const float* __restrict__ t5,
    short* __restrict__ EMBb)
{
    int s = blockIdx.x;
    __shared__ int xi[6];
    if (threadIdx.x < 6) xi[threadIdx.x] = x[s * 6 + threadIdx.x];
    __syncthreads();
    for (int j = threadIdx.x; j < 768; j += 256) {
        int i, off, width; const float* t; float sc;
        if (j < 32)       { i = 0; off = 0;   t = t0; sc = 5.656854249f;  width = 32;  }
        else if (j < 160) { i = 1; off = 32;  t = t1; sc = 11.3137085f;   width = 128; }
        else if (j < 416) { i = 2; off = 160; t = t2; sc = 16.0f;         width = 256; }
        else if (j < 672) { i = 3; off = 416; t = t3; sc = 16.0f;         width = 256; }
        else if (j < 704) { i = 4; off = 672; t = t4; sc = 5.656854249f;  width = 32;  }
        else              { i = 5; off = 704; t = t5; sc = 8.0f;          width = 64;  }
        EMBb[s * 768 + j] = f2bf(t[xi[i] * width + (j - off)] * sc);
    }
}

// ---------------- weight transpose+convert: f32 [B][K][N] -> bf16 [B][N][K] ----
__global__ __launch_bounds__(256) void transpose_w(
    const float* __restrict__ in, short* __restrict__ out, int K, int N)
{
    __shared__ short t[64][66];
    const int b = blockIdx.z;
    const int n0 = blockIdx.x * 64, k0 = blockIdx.y * 64;
    const float* ip = in + (size_t)b * K * N;
    short* op = out + (size_t)b * K * N;
    const int c = threadIdx.x & 63, r0 = (threadIdx.x >> 6) * 16;
    #pragma unroll
    for (int i = 0; i < 16; ++i)
        t[c][r0 + i] = f2bf(ip[(size_t)(k0 + r0 + i) * N + n0 + c]);
    __syncthreads();
    #pragma unroll
    for (int i = 0; i < 16; ++i)
        op[(size_t)(n0 + r0 + i) * K + k0 + c] = t[r0 + i][c];
}

// ---------------- activation ----------------
__device__ __forceinline__ float apply_act(float v, int act) {
    if (act == ACT_PHI)       return (v > 0.0f) ? (v + 1.0f) : expf(v);
    else if (act == ACT_GELU) return 0.5f * v * (1.0f + erff(v * 0.70710678118654752f));
    return v;
}

// ---------------- 128x128 MFMA GEMM core (shared by gemm128/qkv128) --------
// LDS tile: [128 rows][64 k] bf16, 16 KB, XOR-swizzled: byte col ^= (row&7)<<4.
// global_load_lds writes linearly (wave-uniform base + lane*16), so the
// swizzle is applied by permuting the *global source* address (rule #21:
// both-sides-or-neither), and again on the ds_read side.

__device__ __forceinline__ void stage128(
    const short* __restrict__ G, int row0, int ldk, int k0,
    short* lds, int tid)
{
    const int w = tid >> 6;
    #pragma unroll
    for (int i = 0; i < 4; ++i) {
        int o = i * 4096 + tid * 16;                 // linear byte offset in tile
        int row = o >> 7;
        int colb = (o & 127) ^ ((row & 7) << 4);     // inverse-swizzled source
        const char* g = (const char*)(G + (size_t)(row0 + row) * ldk + k0) + colb;
        __builtin_amdgcn_global_load_lds(
            (const __attribute__((address_space(1))) void*)g,
            (__attribute__((address_space(3))) void*)(lds + i * 2048 + w * 512),
            16, 0, 0);
    }
}

__device__ __forceinline__ void compute_tile(
    const short* __restrict__ As, const short* __restrict__ Bs,
    int wr, int wc, int l15, int q, f32x4 acc[4][4])
{
    #pragma unroll
    for (int kh = 0; kh < 2; ++kh) {
        s16x8 a[4], b[4];
        #pragma unroll
        for (int m = 0; m < 4; ++m) {
            int row = wr * 64 + m * 16 + l15;
            int cb = (kh * 64 + q * 16) ^ ((row & 7) << 4);
            a[m] = *(const s16x8*)((const char*)As + row * 128 + cb);
        }
        #pragma unroll
        for (int n = 0; n < 4; ++n) {
            int row = wc * 64 + n * 16 + l15;
            int cb = (kh * 64 + q * 16) ^ ((row & 7) << 4);
            b[n] = *(const s16x8*)((const char*)Bs + row * 128 + cb);
        }
        #pragma unroll
        for (int m = 0; m < 4; ++m)
            #pragma unroll
            for (int n = 0; n < 4; ++n)
                acc[m][n] = __builtin_amdgcn_mfma_f32_16x16x32_bf16(
                    a[m], b[n], acc[m][n], 0, 0, 0);
    }
}

// ---------------- generic GEMM: C[M=1024][N] = A[M][K] @ BT[N][K]^T --------
__global__ __launch_bounds__(256) void gemm128(
    const short* __restrict__ A, const short* __restrict__ BT,
    const float* __restrict__ bias, const float* __restrict__ resid,
    float* __restrict__ Cf, short* __restrict__ Cbf,
    int N, int K, int act, int add_pe)
{
    __shared__ short As[2][8192];
    __shared__ short Bs[2][8192];
    const int tid = threadIdx.x;
    const int row0 = blockIdx.y * 128, col0 = blockIdx.x * 128;
    const int w = tid >> 6, lane = tid & 63, q = lane >> 4, l15 = lane & 15;
    const int wr = w >> 1, wc = w & 1;
    const int nt = K >> 6;

    stage128(A,  row0, K, 0, As[0], tid);
    stage128(BT, col0, K, 0, Bs[0], tid);
    __syncthreads();

    f32x4 acc[4][4] = {};
    int cur = 0;
    for (int t = 0; t < nt; ++t) {
        if (t + 1 < nt) {
            stage128(A,  row0, K, (t + 1) << 6, As[cur ^ 1], tid);
            stage128(BT, col0, K, (t + 1) << 6, Bs[cur ^ 1], tid);
        }
        compute_tile(As[cur], Bs[cur], wr, wc, l15, q, acc);
        __syncthreads();                 // drains vmcnt (stage) + lgkm (reads)
        cur ^= 1;
    }

    const int rbase = row0 + wr * 64 + q * 4;
    const int cbase = col0 + wc * 64 + l15;
    #pragma unroll
    for (int n = 0; n < 4; ++n) {
        int c = cbase + n * 16;
        float bia = bias[c];
        #pragma unroll
        for (int m = 0; m < 4; ++m) {
            #pragma unroll
            for (int rg = 0; rg < 4; ++rg) {
                int r = rbase + m * 16 + rg;
                float v = apply_act(acc[m][n][rg] + bia, act);
                if (resid) v += resid[(size_t)r * N + c];
                if (add_pe) {
                    float freq = expf((float)(c & ~1) * (-9.210340371976184f / 512.0f));
                    float ang = (float)r * freq;
                    v += (c & 1) ? cosf(ang) : sinf(ang);
                }
                if (Cf)  Cf[(size_t)r * N + c] = v;
                if (Cbf) Cbf[(size_t)r * N + c] = f2bf(v);
            }
        }
    }
}

// ---------------- fused QKV: grid (12, 8); phi on Q,K ----------------
__global__ __launch_bounds__(256) void qkv128(
    const short* __restrict__ Hb,
    const short* __restrict__ qT, const short* __restrict__ kT, const short* __restrict__ vT,
    const float* __restrict__ bq, const float* __restrict__ bk, const float* __restrict__ bv,
    float* __restrict__ Qb, float* __restrict__ Kb, float* __restrict__ Vb)
{
    __shared__ short As[2][8192];
    __shared__ short Bs[2][8192];
    const int sel  = blockIdx.x >> 2;              // 0=Q 1=K 2=V
    const int col0 = (blockIdx.x & 3) * 128;
    const int row0 = blockIdx.y * 128;
    const short* BT   = (sel == 0) ? qT : (sel == 1) ? kT : vT;
    const float* bias = (sel == 0) ? bq : (sel == 1) ? bk : bv;
    float* C          = (sel == 0) ? Qb : (sel == 1) ? Kb : Vb;
    const bool phi = (sel < 2);

    const int tid = threadIdx.x;
    const int w = tid >> 6, lane = tid & 63, q = lane >> 4, l15 = lane & 15;
    const int wr = w >> 1, wc = w & 1;

    stage128(Hb, row0, DM, 0, As[0], tid);
    stage128(BT, col0, DM, 0, Bs[0], tid);
    __syncthreads();

    f32x4 acc[4][4] = {};
    int cur = 0;
    for (int t = 0; t < 8; ++t) {                  // K = 512 -> 8 tiles
        if (t + 1 < 8) {
            stage128(Hb, row0, DM, (t + 1) << 6, As[cur ^ 1], tid);
            stage128(BT, col0, DM, (t + 1) << 6, Bs[cur ^ 1], tid);
        }
        compute_tile(As[cur], Bs[cur], wr, wc, l15, q, acc);
        __syncthreads();
        cur ^= 1;
    }

    const int rbase = row0 + wr * 64 + q * 4;
    const int cbase = col0 + wc * 64 + l15;
    #pragma unroll
    for (int n = 0; n < 4; ++n) {
        int c = cbase + n * 16;
        float bia = bias[c];
        #pragma unroll
        for (int m = 0; m < 4; ++m) {
            #pragma unroll
            for (int rg = 0; rg < 4; ++rg) {
                int r = rbase + m * 16 + rg;
                float v = acc[m][n][rg] + bia;
                if (phi) v = (v > 0.0f) ? (v + 1.0f) : expf(v);
                C[(size_t)r * DM + c] = v;
            }
        }
    }
}

// ---------------- chunk stats: per (head, chunk) KV_c = K_c^T V_c, ksum_c ----
// Register-tiled: thread (di, ei) owns a 4x4 tile of the 64x64 K^T V product.
__global__ __launch_bounds__(256) void chunk_stats_kernel(
    const float* __restrict__ Kb, const float* __restrict__ Vb,
    float* __restrict__ KVC, float* __restrict__ KSC)
{
    const int h = blockIdx.x >> 4, c = blockIdx.x & 15;
    const int tid = threadIdx.x;
    __shared__ float Ks[64][68];
    __shared__ float Vs[64][68];
    #pragma unroll
    for (int it = 0; it < 4; ++it) {
        int j = tid + it * 256;                 // 0..1023 f32x4 slots
        int r = j >> 4, d0 = (j & 15) * 4;
        size_t g = (size_t)(c * CHUNK + r) * DM + h * 64 + d0;
        *(f32x4*)(&Ks[r][d0]) = *(const f32x4*)(Kb + g);
        *(f32x4*)(&Vs[r][d0]) = *(const f32x4*)(Vb + g);
    }
    __syncthreads();
    const int di = (tid >> 4) * 4, ei = (tid & 15) * 4;
    f32x4 a0 = {}, a1 = {}, a2 = {}, a3 = {}, ks = {};
    #pragma unroll 8
    for (int t = 0; t < 64; ++t) {
        f32x4 kk = *(const f32x4*)(&Ks[t][di]);
        f32x4 vv = *(const f32x4*)(&Vs[t][ei]);
        fma4(a0, kk.x, vv); fma4(a1, kk.y, vv);
        fma4(a2, kk.z, vv); fma4(a3, kk.w, vv);
        ks += kk;
    }
    float* out = KVC + (size_t)(c * NH + h) * 4096;   // [d][e] row-major
    *(f32x4*)(out + (size_t)(di + 0) * 64 + ei) = a0;
    *(f32x4*)(out + (size_t)(di + 1) * 64 + ei) = a1;
    *(f32x4*)(out + (size_t)(di + 2) * 64 + ei) = a2;
    *(f32x4*)(out + (size_t)(di + 3) * 64 + ei) = a3;
    if ((tid & 15) == 0)
        *(f32x4*)(KSC + (size_t)(c * NH + h) * 64 + di) = ks;
}

// ---------------- in-place exclusive prefix scan over chunks ----------------
__global__ __launch_bounds__(256) void scan_kv_kernel(
    float* __restrict__ KVC, float* __restrict__ KSC)
{
    int gid = blockIdx.x * 256 + threadIdx.x;   // 8192 threads
    int h = gid >> 10, e4 = gid & 1023;
    f32x4* p = (f32x4*)KVC;
    f32x4 run = {};
    #pragma unroll
    for (int c = 0; c < NCH; ++c) {
        size_t idx = (size_t)(c * NH + h) * 1024 + e4;
        f32x4 v = p[idx];
        p[idx] = run;
        run += v;
    }
    if (gid < NH * 64) {
        int h2 = gid >> 6, e = gid & 63;
        float r = 0.0f;
        for (int c = 0; c < NCH; ++c) {
            size_t idx = (size_t)(c * NH + h2) * 64 + e;
            float v = KSC[idx];
            KSC[idx] = r;
            r += v;
        }
    }
}

// ---------------- attention output per (head, chunk) ----------------
__global__ __launch_bounds__(256) void attn_out_kernel(
    const float* __restrict__ Qb, const float* __restrict__ Kb,
    const float* __restrict__ Vb, const float* __restrict__ KVC,
    const float* __restrict__ KSC, short* __restrict__ Ab)
{
    const int h = blockIdx.x >> 4, c = blockIdx.x & 15;
    const int tid = threadIdx.x;
    __shared__ float Qt[64][68];   // Qt[d][s]  (transposed)
    __shared__ float Kt[64][68];   // Kt[d][t]  (transposed)
    __shared__ float Vs[64][68];   // Vs[t][e]
    __shared__ float Ms[64][68];   // state: Ms[d][e]
    __shared__ float St[64][68];   // St[t][s]  (S transposed)
    __shared__ float KSs[64];

    const float* ms_src = KVC + (size_t)(c * NH + h) * 4096;
    #pragma unroll
    for (int it = 0; it < 4; ++it) {
        int j = tid + it * 256;                 // 0..1023
        int r = j >> 4, d0 = (j & 15) * 4;
        size_t g = (size_t)(c * CHUNK + r) * DM + h * 64 + d0;
        f32x4 q = *(const f32x4*)(Qb + g);
        f32x4 k = *(const f32x4*)(Kb + g);
        f32x4 v = *(const f32x4*)(Vb + g);
        Qt[d0 + 0][r] = q.x; Qt[d0 + 1][r] = q.y; Qt[d0 + 2][r] = q.z; Qt[d0 + 3][r] = q.w;
        Kt[d0 + 0][r] = k.x; Kt[d0 + 1][r] = k.y; Kt[d0 + 2][r] = k.z; Kt[d0 + 3][r] = k.w;
        *(f32x4*)(&Vs[r][d0]) = v;
        *(f32x4*)(&Ms[r][d0]) = *(const f32x4*)(ms_src + (size_t)j * 4);
    }
    if (tid < 64) KSs[tid] = KSC[(size_t)(c * NH + h) * 64 + tid];
    __syncthreads();

    const int si = tid >> 4, ti = tid & 15;
    const int s0 = si * 4, t0 = ti * 4;         // t0 doubles as e0

    // ---- Phase A: inter-chunk O = Q @ State, den = Q . KSprefix ----
    f32x4 accO0 = {}, accO1 = {}, accO2 = {}, accO3 = {};
    f32x4 den = {};
    #pragma unroll 8
    for (int d = 0; d < 64; ++d) {
        f32x4 qv = *(const f32x4*)(&Qt[d][s0]);
        f32x4 mv = *(const f32x4*)(&Ms[d][t0]);
        float ks = KSs[d];
        fma4(accO0, qv.x, mv); fma4(accO1, qv.y, mv);
        fma4(accO2, qv.z, mv); fma4(accO3, qv.w, mv);
        fma4(den, ks, qv);
    }

    // ---- Phase B: S = Q K^T, causal, staged transposed ----
    f32x4 p0 = {}, p1 = {}, p2 = {}, p3 = {};   // p_r = S[s0+r][t0:t0+4]
    if (ti <= si) {
        #pragma unroll 8
        for (int d = 0; d < 64; ++d) {
            f32x4 qv = *(const f32x4*)(&Qt[d][s0]);
            f32x4 kv = *(const f32x4*)(&Kt[d][t0]);
            fma4(p0, qv.x, kv); fma4(p1, qv.y, kv);
            fma4(p2, qv.z, kv); fma4(p3, qv.w, kv);
        }
        if (ti == si) {                          // diagonal tile: keep t<=r
            p0.y = 0.0f; p0.z = 0.0f; p0.w = 0.0f;
            p1.z = 0.0f; p1.w = 0.0f;
            p2.w = 0.0f;
        }
    }
    St[t0 + 0][s0 + 0] = p0.x; St[t0 + 1][s0 + 0] = p0.y;
    St[t0 + 2][s0 + 0] = p0.z; St[t0 + 3][s0 + 0] = p0.w;
    St[t0 + 0][s0 + 1] = p1.x; St[t0 + 1][s0 + 1] = p1.y;
    St[t0 + 2][s0 + 1] = p1.z; St[t0 + 3][s0 + 1] = p1.w;
    St[t0 + 0][s0 + 2] = p2.x; St[t0 + 1][s0 + 2] = p2.y;
    St[t0 + 2][s0 + 2] = p2.z; St[t0 + 3][s0 + 2] = p2.w;
    St[t0 + 0][s0 + 3] = p3.x; St[t0 + 1][s0 + 3] = p3.y;
    St[t0 + 2][s0 + 3] = p3.z; St[t0 + 3][s0 + 3] = p3.w;
    __syncthreads();

    // ---- Phase C: O += S @ V ; den += rowsum(S) ----
    const int tmax = s0 + 4;                     // exclusive; St zero above diag
    #pragma unroll 4
    for (int t2 = 0; t2 < tmax; ++t2) {
        f32x4 sv = *(const f32x4*)(&St[t2][s0]);
        f32x4 vv = *(const f32x4*)(&Vs[t2][t0]);
        fma4(accO0, sv.x, vv); fma4(accO1, sv.y, vv);
        fma4(accO2, sv.z, vv); fma4(accO3, sv.w, vv);
        den += sv;
    }

    // ---- epilogue: z = 1/(den+eps), bf16 out ----
    short* op = Ab + (size_t)(c * CHUNK + s0) * DM + h * 64 + t0;
    {
        float z = 1.0f / (den.x + 1e-6f);
        short4 o; o.x = f2bf(accO0.x * z); o.y = f2bf(accO0.y * z);
        o.z = f2bf(accO0.z * z); o.w = f2bf(accO0.w * z);
        *reinterpret_cast<short4*>(op) = o;
    }
    {
        float z = 1.0f / (den.y + 1e-6f);
        short4 o; o.x = f2bf(accO1.x * z); o.y = f2bf(accO1.y * z);
        o.z = f2bf(accO1.z * z); o.w = f2bf(accO1.w * z);
        *reinterpret_cast<short4*>(op + DM) = o;
    }
    {
        float z = 1.0f / (den.z + 1e-6f);
        short4 o; o.x = f2bf(accO2.x * z); o.y = f2bf(accO2.y * z);
        o.z = f2bf(accO2.z * z); o.w = f2bf(accO2.w * z);
        *reinterpret_cast<short4*>(op + 2 * DM) = o;
    }
    {
        float z = 1.0f / (den.w + 1e-6f);
        short4 o; o.x = f2bf(accO3.x * z); o.y = f2bf(accO3.y * z);
        o.z = f2bf(accO3.z * z); o.w = f2bf(accO3.w * z);
        *reinterpret_cast<short4*>(op + 3 * DM) = o;
    }
}

// ---------------- layernorm (fp32 out + optional bf16 mirror) ----------------
__device__ __forceinline__ float block_reduce_sum(float v, float* smem)
{
    #pragma unroll
    for (int o = 32; o > 0; o >>= 1) v += __shfl_down(v, o, 64);
    int w = threadIdx.x >> 6;
    if ((threadIdx.x & 63) == 0) smem[w] = v;
    __syncthreads();
    v = smem[0] + smem[1] + smem[2] + smem[3];
    __syncthreads();
    return v;
}

__global__ __launch_bounds__(256) void ln_kernel(
    const float* __restrict__ X, const float* __restrict__ g,
    const float* __restrict__ b, float* __restrict__ O, short* __restrict__ Ob)
{
    __shared__ float red[4];
    const int row = blockIdx.x;
    const float* x = X + (size_t)row * DM;
    const int t = threadIdx.x;
    float v0 = x[t], v1 = x[t + 256];
    float mean = block_reduce_sum(v0 + v1, red) * (1.0f / 512.0f);
    float d0 = v0 - mean, d1 = v1 - mean;
    float var = block_reduce_sum(d0 * d0 + d1 * d1, red) * (1.0f / 512.0f);
    float rs = 1.0f / sqrtf(var + 1e-5f);
    float o0 = d0 * rs * g[t] + b[t];
    float o1 = d1 * rs * g[t + 256] + b[t + 256];
    O[(size_t)row * DM + t]       = o0;
    O[(size_t)row * DM + t + 256] = o1;
    if (Ob) {
        Ob[(size_t)row * DM + t]       = f2bf(o0);
        Ob[(size_t)row * DM + t + 256] = f2bf(o1);
    }
}

// ---------------- emotion head: [1024,512] @ [512,8] + b ----------------
__global__ __launch_bounds__(256) void proj_emo_kernel(
    const float* __restrict__ HF, const float* __restrict__ pw,
    const float* __restrict__ pb, float* __restrict__ out)
{
    int idx = blockIdx.x * 256 + threadIdx.x;
    int r = idx >> 3, e = idx & 7;
    float acc = pb[e];
    const float* h = HF + (size_t)r * DM;
    for (int d = 0; d < DM; ++d) acc += h[d] * pw[d * 8 + e];
    out[idx] = acc;
}

// ---------------------------------------------------------------------------
extern "C" void kernel_launch(void* const* d_in, const int* in_sizes, int n_in,
                              void* d_out, int out_size, void* d_ws, size_t ws_size,
                              hipStream_t stream)
{
    const int*   x    = (const int*)d_in[0];
    const float* e0   = (const float*)d_in[1];
    const float* e1   = (const float*)d_in[2];
    const float* e2   = (const float*)d_in[3];
    const float* e3   = (const float*)d_in[4];
    const float* e4   = (const float*)d_in[5];
    const float* e5   = (const float*)d_in[6];
    const float* in_w = (const float*)d_in[7];
    const float* in_b = (const float*)d_in[8];
    const float* wq   = (const float*)d_in[9];
    const float* bq   = (const float*)d_in[10];
    const float* wk   = (const float*)d_in[11];
    const float* bk   = (const float*)d_in[12];
    const float* wv   = (const float*)d_in[13];
    const float* bv   = (const float*)d_in[14];
    const float* wo   = (const float*)d_in[15];
    const float* bo   = (const float*)d_in[16];
    const float* g1   = (const float*)d_in[17];
    const float* be1  = (const float*)d_in[18];
    const float* w1   = (const float*)d_in[19];
    const float* b1   = (const float*)d_in[20];
    const float* w2   = (const float*)d_in[21];
    const float* b2   = (const float*)d_in[22];
    const float* g2   = (const float*)d_in[23];
    const float* be2  = (const float*)d_in[24];
    const float* gf   = (const float*)d_in[25];
    const float* bfin = (const float*)d_in[26];
    const float* pw   = (const float*)d_in[27];
    const float* pb   = (const float*)d_in[28];
    float* outp = (float*)d_out;

    // ---- workspace layout (unchanged from R10) ----
    float* ws = (float*)d_ws;
    float* H    = ws;                  // 1024x512 f32
    float* Y    = ws + 524288;         // 1024x512 f32
    float* Qb   = ws + 1048576;
    float* Kb   = ws + 1572864;
    float* Vb   = ws + 2097152;
    float* KVC  = ws + 2621440;        // 16*8*4096 = 524288
    float* KSC  = ws + 3145728;        // 8192 (f32 end: 3153920 floats)
    short* sb   = (short*)(ws + 3153920);
    short* Hb   = sb;                  // 1024x512
    short* Ab   = sb + 524288;         // 1024x512
    short* FFb  = sb + 1048576;        // 1024x2048
    short* EMBb = FFb;                 // 1024x768 (alias: dead before ffn1)
    // bf16 W^T arena [N][K]
    short* inT  = sb + 3145728;        // [512][768]
    short* qT   = inT + 393216;        // [12][512][512]
    short* kT   = qT + 3145728;
    short* vT   = kT + 3145728;
    short* oT   = vT + 3145728;
    short* w1T  = oT + 3145728;        // [12][2048][512]
    short* w2T  = w1T + 12582912;      // [12][512][2048]  (total ~90.8 MB)

    const dim3 blk256(256);

    // ---- weight transpose+convert ----
    transpose_w<<<dim3(8, 12, 1),  blk256, 0, stream>>>(in_w, inT, 768, DM);
    transpose_w<<<dim3(8, 8, 12),  blk256, 0, stream>>>(wq, qT, DM, DM);
    transpose_w<<<dim3(8, 8, 12),  blk256, 0, stream>>>(wk, kT, DM, DM);
    transpose_w<<<dim3(8, 8, 12),  blk256, 0, stream>>>(wv, vT, DM, DM);
    transpose_w<<<dim3(8, 8, 12),  blk256, 0, stream>>>(wo, oT, DM, DM);
    transpose_w<<<dim3(32, 8, 12), blk256, 0, stream>>>(w1, w1T, DM, DFF);
    transpose_w<<<dim3(8, 32, 12), blk256, 0, stream>>>(w2, w2T, DFF, DM);

    embed_kernel<<<S_LEN, blk256, 0, stream>>>(x, e0, e1, e2, e3, e4, e5, EMBb);
    // in-proj: EMBb @ in_w + in_b + PE -> H (f32) and Hb (bf16)
    gemm128<<<dim3(4, 8), blk256, 0, stream>>>(EMBb, inT, in_b, nullptr,
                                               H, Hb, DM, 768, ACT_NONE, 1);

    for (int l = 0; l < NLAYER; ++l) {
        const short* qT_l = qT + (size_t)l * DM * DM;
        const short* kT_l = kT + (size_t)l * DM * DM;
        const short* vT_l = vT + (size_t)l * DM * DM;
        const short* oT_l = oT + (size_t)l * DM * DM;
        const short* w1T_l = w1T + (size_t)l * DM * DFF;
        const short* w2T_l = w2T + (size_t)l * DM * DFF;
        const float* bq_l = bq + l * DM;  const float* bk_l = bk + l * DM;
        const float* bv_l = bv + l * DM;  const float* bo_l = bo + l * DM;
        const float* b1_l = b1 + l * DFF; const float* b2_l = b2 + l * DM;

        qkv128<<<dim3(12, 8), blk256, 0, stream>>>(Hb, qT_l, kT_l, vT_l,
                                                   bq_l, bk_l, bv_l, Qb, Kb, Vb);

        chunk_stats_kernel<<<NCH * NH, blk256, 0, stream>>>(Kb, Vb, KVC, KSC);
        scan_kv_kernel<<<32, blk256, 0, stream>>>(KVC, KSC);
        attn_out_kernel<<<NCH * NH, blk256, 0, stream>>>(Qb, Kb, Vb, KVC, KSC, Ab);

        // wo: Ab @ wo + bo + resid(H) -> Y (f32); then LN -> H, Hb
        gemm128<<<dim3(4, 8), blk256, 0, stream>>>(Ab, oT_l, bo_l, H,
                                                   Y, nullptr, DM, DM, ACT_NONE, 0);
        ln_kernel<<<S_LEN, blk256, 0, stream>>>(Y, g1 + l * DM, be1 + l * DM, H, Hb);

        // ffn1: Hb @ w1 + b1, GELU -> FFb (bf16)
        gemm128<<<dim3(16, 8), blk256, 0, stream>>>(Hb, w1T_l, b1_l, nullptr,
                                                    nullptr, FFb, DFF, DM, ACT_GELU, 0);
        // ffn2: FFb @ w2 + b2 + resid(H) -> Y (f32); then LN -> H, Hb
        gemm128<<<dim3(4, 8), blk256, 0, stream>>>(FFb, w2T_l, b2_l, H,
                                                   Y, nullptr, DM, DFF, ACT_NONE, 0);
        ln_kernel<<<S_LEN, blk256, 0, stream>>>(Y, g2 + l * DM, be2 + l * DM, H, Hb);
    }

    // final norm -> d_out (f32 h), then emotion head
    ln_kernel<<<S_LEN, blk256, 0, stream>>>(H, gf, bfin, outp, nullptr);
    proj_emo_kernel<<<8192 / 256, blk256, 0, stream>>>(outp, pw, pb, outp + 524288);
}

// Round 3
// 1179.439 us; speedup vs baseline: 1.9566x; 1.9566x over previous
//
#include <hip/hip_runtime.h>
#include <hip/hip_bf16.h>
#include <math.h>

// ---------------------------------------------------------------------------
// TransformerModel: 12-layer causal linear-attention encoder.
// B=1, S=1024, D_MODEL=512, H=8, Dh=64, FF=2048. All tensors fp32 (x int32).
// Round 12: R11's gemm128 (global_load_lds, 128^2 tiles) was latency-dead
// (MfmaUtil 0.4%, occupancy 1.3%: 32-block grids + waterfall'd LDS-dest).
// gemm64: 64x64 tile / 256 thr / 4 waves (32x32 per wave, gemm32's proven
// fragment+epilogue), BK=64, reg-staged global->LDS (dwordx4 + ds_write_b128),
// double-buffer with ONE barrier/iter, XOR swizzle (bytecol ^= (row&7)<<4)
// on both ds_write and ds_read. Grids: 128-512 blocks (vs 32).
// Attention / LN / embed / transpose unchanged (bisection).
// ---------------------------------------------------------------------------

#define S_LEN 1024
#define DM 512
#define NH 8
#define DH 64
#define DFF 2048
#define NLAYER 12
#define CHUNK 64
#define NCH (S_LEN / CHUNK)   // 16

#define ACT_NONE 0
#define ACT_PHI  1
#define ACT_GELU 2

typedef short s16x8 __attribute__((ext_vector_type(8)));
typedef float f32x4 __attribute__((ext_vector_type(4)));

__device__ __forceinline__ short f2bf(float x) {
    __hip_bfloat16 h = __float2bfloat16(x);
    return *reinterpret_cast<short*>(&h);
}

__device__ __forceinline__ void fma4(f32x4& a, float s, const f32x4 v) {
    a.x = fmaf(s, v.x, a.x); a.y = fmaf(s, v.y, a.y);
    a.z = fmaf(s, v.z, a.z); a.w = fmaf(s, v.w, a.w);
}

// ---------------- embedding gather (writes bf16) ----------------
__global__ __launch_bounds__(256) void embed_kernel(
    const int* __restrict__ x,
    const float* __restrict__ t0, const float* __restrict__ t1,
    const float* __restrict__ t2, const float* __restrict__ t3,
    const float* __restrict__ t4, const float* __restrict__ t5,
    short* __restrict__ EMBb)
{
    int s = blockIdx.x;
    __shared__ int xi[6];
    if (threadIdx.x < 6) xi[threadIdx.x] = x[s * 6 + threadIdx.x];
    __syncthreads();
    for (int j = threadIdx.x; j < 768; j += 256) {
        int i, off, width; const float* t; float sc;
        if (j < 32)       { i = 0; off = 0;   t = t0; sc = 5.656854249f;  width = 32;  }
        else if (j < 160) { i = 1; off = 32;  t = t1; sc = 11.3137085f;   width = 128; }
        else if (j < 416) { i = 2; off = 160; t = t2; sc = 16.0f;         width = 256; }
        else if (j < 672) { i = 3; off = 416; t = t3; sc = 16.0f;         width = 256; }
        else if (j < 704) { i = 4; off = 672; t = t4; sc = 5.656854249f;  width = 32;  }
        else              { i = 5; off = 704; t = t5; sc = 8.0f;          width = 64;  }
        EMBb[s * 768 + j] = f2bf(t[xi[i] * width + (j - off)] * sc);
    }
}

// ---------------- weight transpose+convert: f32 [B][K][N] -> bf16 [B][N][K] ----
__global__ __launch_bounds__(256) void transpose_w(
    const float* __restrict__ in, short* __restrict__ out, int K, int N)
{
    __shared__ short t[64][66];
    const int b = blockIdx.z;
    const int n0 = blockIdx.x * 64, k0 = blockIdx.y * 64;
    const float* ip = in + (size_t)b * K * N;
    short* op = out + (size_t)b * K * N;
    const int c = threadIdx.x & 63, r0 = (threadIdx.x >> 6) * 16;
    #pragma unroll
    for (int i = 0; i < 16; ++i)
        t[c][r0 + i] = f2bf(ip[(size_t)(k0 + r0 + i) * N + n0 + c]);
    __syncthreads();
    #pragma unroll
    for (int i = 0; i < 16; ++i)
        op[(size_t)(n0 + r0 + i) * K + k0 + c] = t[r0 + i][c];
}

// ---------------- activation ----------------
__device__ __forceinline__ float apply_act(float v, int act) {
    if (act == ACT_PHI)       return (v > 0.0f) ? (v + 1.0f) : expf(v);
    else if (act == ACT_GELU) return 0.5f * v * (1.0f + erff(v * 0.70710678118654752f));
    return v;
}

// ---------------- 64x64-tile MFMA GEMM core -------------------------------
// LDS tile: [64 rows][64 k] bf16 = 8KB, double-buffered for A and B (32KB).
// Bank swizzle: byte col ^= (row&7)<<4 on BOTH ds_write and ds_read.
// Staging: thread tid loads 16B; pass p covers rows p*32 + (tid>>3),
// byte col (tid&7)*16. Reg-staged: global_load_dwordx4 -> ds_write_b128,
// prefetch issued one iteration ahead (latency hides under compute).

__device__ __forceinline__ void ldswr64(short* lds, int srow, int scolb,
                                        const s16x8 r[2])
{
    const int bc = scolb ^ ((srow & 7) << 4);
    #pragma unroll
    for (int p = 0; p < 2; ++p)
        *(s16x8*)((char*)lds + (p * 32 + srow) * 128 + bc) = r[p];
}

__device__ __forceinline__ void compute64(
    const short* __restrict__ As, const short* __restrict__ Bs,
    int wr, int wc, int l15, int q, f32x4 acc[2][2])
{
    #pragma unroll
    for (int kh = 0; kh < 2; ++kh) {
        const int kb = kh * 64 + q * 16;
        s16x8 a[2], b[2];
        #pragma unroll
        for (int m = 0; m < 2; ++m) {
            int row = wr * 32 + m * 16 + l15;
            a[m] = *(const s16x8*)((const char*)As + row * 128 + (kb ^ ((row & 7) << 4)));
        }
        #pragma unroll
        for (int n = 0; n < 2; ++n) {
            int row = wc * 32 + n * 16 + l15;
            b[n] = *(const s16x8*)((const char*)Bs + row * 128 + (kb ^ ((row & 7) << 4)));
        }
        #pragma unroll
        for (int m = 0; m < 2; ++m)
            #pragma unroll
            for (int n = 0; n < 2; ++n)
                acc[m][n] = __builtin_amdgcn_mfma_f32_16x16x32_bf16(
                    a[m], b[n], acc[m][n], 0, 0, 0);
    }
}

// ---------------- generic GEMM: C[1024][N] = A[1024][K] @ BT[N][K]^T -------
__global__ __launch_bounds__(256) void gemm64(
    const short* __restrict__ A, const short* __restrict__ BT,
    const float* __restrict__ bias, const float* __restrict__ resid,
    float* __restrict__ Cf, short* __restrict__ Cbf,
    int N, int K, int act, int add_pe)
{
    __shared__ short As[2][4096];
    __shared__ short Bs[2][4096];
    const int tid = threadIdx.x;
    const int row0 = blockIdx.y * 64, col0 = blockIdx.x * 64;
    const int w = tid >> 6, lane = tid & 63, q = lane >> 4, l15 = lane & 15;
    const int wr = w >> 1, wc = w & 1;
    const int nt = K >> 6;

    const int srow = tid >> 3;              // 0..31
    const int scolb = (tid & 7) * 16;       // 0..112 bytes
    const char* gA = (const char*)(A  + (size_t)(row0 + srow) * K) + scolb;
    const char* gB = (const char*)(BT + (size_t)(col0 + srow) * K) + scolb;
    const size_t rstep = (size_t)32 * K * 2;   // +32 rows, bytes

    s16x8 ra[2], rb[2];
    #pragma unroll
    for (int p = 0; p < 2; ++p) {
        ra[p] = *(const s16x8*)(gA + p * rstep);
        rb[p] = *(const s16x8*)(gB + p * rstep);
    }
    ldswr64(As[0], srow, scolb, ra);
    ldswr64(Bs[0], srow, scolb, rb);
    if (nt > 1) {
        #pragma unroll
        for (int p = 0; p < 2; ++p) {
            ra[p] = *(const s16x8*)(gA + p * rstep + 128);
            rb[p] = *(const s16x8*)(gB + p * rstep + 128);
        }
    }
    __syncthreads();

    f32x4 acc[2][2] = {};
    int cur = 0;
    for (int t = 0; t < nt; ++t) {
        if (t + 1 < nt) {                         // regs hold tile t+1
            ldswr64(As[cur ^ 1], srow, scolb, ra);
            ldswr64(Bs[cur ^ 1], srow, scolb, rb);
        }
        if (t + 2 < nt) {                         // prefetch tile t+2
            size_t ko = (size_t)(t + 2) * 128;
            #pragma unroll
            for (int p = 0; p < 2; ++p) {
                ra[p] = *(const s16x8*)(gA + p * rstep + ko);
                rb[p] = *(const s16x8*)(gB + p * rstep + ko);
            }
        }
        compute64(As[cur], Bs[cur], wr, wc, l15, q, acc);
        __syncthreads();
        cur ^= 1;
    }

    const int rbase = row0 + wr * 32 + q * 4;
    const int cbase = col0 + wc * 32 + l15;
    #pragma unroll
    for (int n = 0; n < 2; ++n) {
        int c = cbase + n * 16;
        float bia = bias[c];
        #pragma unroll
        for (int m = 0; m < 2; ++m) {
            #pragma unroll
            for (int rg = 0; rg < 4; ++rg) {
                int r = rbase + m * 16 + rg;
                float v = apply_act(acc[m][n][rg] + bia, act);
                if (resid) v += resid[(size_t)r * N + c];
                if (add_pe) {
                    float freq = expf((float)(c & ~1) * (-9.210340371976184f / 512.0f));
                    float ang = (float)r * freq;
                    v += (c & 1) ? cosf(ang) : sinf(ang);
                }
                if (Cf)  Cf[(size_t)r * N + c] = v;
                if (Cbf) Cbf[(size_t)r * N + c] = f2bf(v);
            }
        }
    }
}

// ---------------- fused QKV: grid (24, 16); phi on Q,K ----------------
__global__ __launch_bounds__(256) void qkv64(
    const short* __restrict__ Hb,
    const short* __restrict__ qT, const short* __restrict__ kT, const short* __restrict__ vT,
    const float* __restrict__ bq, const float* __restrict__ bk, const float* __restrict__ bv,
    float* __restrict__ Qb, float* __restrict__ Kb, float* __restrict__ Vb)
{
    __shared__ short As[2][4096];
    __shared__ short Bs[2][4096];
    const int sel  = blockIdx.x >> 3;              // 0=Q 1=K 2=V
    const int col0 = (blockIdx.x & 7) * 64;
    const int row0 = blockIdx.y * 64;
    const short* BT   = (sel == 0) ? qT : (sel == 1) ? kT : vT;
    const float* bias = (sel == 0) ? bq : (sel == 1) ? bk : bv;
    float* C          = (sel == 0) ? Qb : (sel == 1) ? Kb : Vb;
    const bool phi = (sel < 2);

    const int tid = threadIdx.x;
    const int w = tid >> 6, lane = tid & 63, q = lane >> 4, l15 = lane & 15;
    const int wr = w >> 1, wc = w & 1;

    const int srow = tid >> 3;
    const int scolb = (tid & 7) * 16;
    const char* gA = (const char*)(Hb + (size_t)(row0 + srow) * DM) + scolb;
    const char* gB = (const char*)(BT + (size_t)(col0 + srow) * DM) + scolb;
    const size_t rstep = (size_t)32 * DM * 2;

    s16x8 ra[2], rb[2];
    #pragma unroll
    for (int p = 0; p < 2; ++p) {
        ra[p] = *(const s16x8*)(gA + p * rstep);
        rb[p] = *(const s16x8*)(gB + p * rstep);
    }
    ldswr64(As[0], srow, scolb, ra);
    ldswr64(Bs[0], srow, scolb, rb);
    #pragma unroll
    for (int p = 0; p < 2; ++p) {
        ra[p] = *(const s16x8*)(gA + p * rstep + 128);
        rb[p] = *(const s16x8*)(gB + p * rstep + 128);
    }
    __syncthreads();

    f32x4 acc[2][2] = {};
    int cur = 0;
    for (int t = 0; t < 8; ++t) {                  // K = 512 -> 8 tiles
        if (t + 1 < 8) {
            ldswr64(As[cur ^ 1], srow, scolb, ra);
            ldswr64(Bs[cur ^ 1], srow, scolb, rb);
        }
        if (t + 2 < 8) {
            size_t ko = (size_t)(t + 2) * 128;
            #pragma unroll
            for (int p = 0; p < 2; ++p) {
                ra[p] = *(const s16x8*)(gA + p * rstep + ko);
                rb[p] = *(const s16x8*)(gB + p * rstep + ko);
            }
        }
        compute64(As[cur], Bs[cur], wr, wc, l15, q, acc);
        __syncthreads();
        cur ^= 1;
    }

    const int rbase = row0 + wr * 32 + q * 4;
    const int cbase = col0 + wc * 32 + l15;
    #pragma unroll
    for (int n = 0; n < 2; ++n) {
        int c = cbase + n * 16;
        float bia = bias[c];
        #pragma unroll
        for (int m = 0; m < 2; ++m) {
            #pragma unroll
            for (int rg = 0; rg < 4; ++rg) {
                int r = rbase + m * 16 + rg;
                float v = acc[m][n][rg] + bia;
                if (phi) v = (v > 0.0f) ? (v + 1.0f) : expf(v);
                C[(size_t)r * DM + c] = v;
            }
        }
    }
}

// ---------------- chunk stats: per (head, chunk) KV_c = K_c^T V_c, ksum_c ----
__global__ __launch_bounds__(256) void chunk_stats_kernel(
    const float* __restrict__ Kb, const float* __restrict__ Vb,
    float* __restrict__ KVC, float* __restrict__ KSC)
{
    const int h = blockIdx.x >> 4, c = blockIdx.x & 15;
    const int tid = threadIdx.x;
    __shared__ float Ks[64][68];
    __shared__ float Vs[64][68];
    #pragma unroll
    for (int it = 0; it < 4; ++it) {
        int j = tid + it * 256;                 // 0..1023 f32x4 slots
        int r = j >> 4, d0 = (j & 15) * 4;
        size_t g = (size_t)(c * CHUNK + r) * DM + h * 64 + d0;
        *(f32x4*)(&Ks[r][d0]) = *(const f32x4*)(Kb + g);
        *(f32x4*)(&Vs[r][d0]) = *(const f32x4*)(Vb + g);
    }
    __syncthreads();
    const int di = (tid >> 4) * 4, ei = (tid & 15) * 4;
    f32x4 a0 = {}, a1 = {}, a2 = {}, a3 = {}, ks = {};
    #pragma unroll 8
    for (int t = 0; t < 64; ++t) {
        f32x4 kk = *(const f32x4*)(&Ks[t][di]);
        f32x4 vv = *(const f32x4*)(&Vs[t][ei]);
        fma4(a0, kk.x, vv); fma4(a1, kk.y, vv);
        fma4(a2, kk.z, vv); fma4(a3, kk.w, vv);
        ks += kk;
    }
    float* out = KVC + (size_t)(c * NH + h) * 4096;   // [d][e] row-major
    *(f32x4*)(out + (size_t)(di + 0) * 64 + ei) = a0;
    *(f32x4*)(out + (size_t)(di + 1) * 64 + ei) = a1;
    *(f32x4*)(out + (size_t)(di + 2) * 64 + ei) = a2;
    *(f32x4*)(out + (size_t)(di + 3) * 64 + ei) = a3;
    if ((tid & 15) == 0)
        *(f32x4*)(KSC + (size_t)(c * NH + h) * 64 + di) = ks;
}

// ---------------- in-place exclusive prefix scan over chunks ----------------
__global__ __launch_bounds__(256) void scan_kv_kernel(
    float* __restrict__ KVC, float* __restrict__ KSC)
{
    int gid = blockIdx.x * 256 + threadIdx.x;   // 8192 threads
    int h = gid >> 10, e4 = gid & 1023;
    f32x4* p = (f32x4*)KVC;
    f32x4 run = {};
    #pragma unroll
    for (int c = 0; c < NCH; ++c) {
        size_t idx = (size_t)(c * NH + h) * 1024 + e4;
        f32x4 v = p[idx];
        p[idx] = run;
        run += v;
    }
    if (gid < NH * 64) {
        int h2 = gid >> 6, e = gid & 63;
        float r = 0.0f;
        for (int c = 0; c < NCH; ++c) {
            size_t idx = (size_t)(c * NH + h2) * 64 + e;
            float v = KSC[idx];
            KSC[idx] = r;
            r += v;
        }
    }
}

// ---------------- attention output per (head, chunk) ----------------
__global__ __launch_bounds__(256) void attn_out_kernel(
    const float* __restrict__ Qb, const float* __restrict__ Kb,
    const float* __restrict__ Vb, const float* __restrict__ KVC,
    const float* __restrict__ KSC, short* __restrict__ Ab)
{
    const int h = blockIdx.x >> 4, c = blockIdx.x & 15;
    const int tid = threadIdx.x;
    __shared__ float Qt[64][68];   // Qt[d][s]  (transposed)
    __shared__ float Kt[64][68];   // Kt[d][t]  (transposed)
    __shared__ float Vs[64][68];   // Vs[t][e]
    __shared__ float Ms[64][68];   // state: Ms[d][e]
    __shared__ float St[64][68];   // St[t][s]  (S transposed)
    __shared__ float KSs[64];

    const float* ms_src = KVC + (size_t)(c * NH + h) * 4096;
    #pragma unroll
    for (int it = 0; it < 4; ++it) {
        int j = tid + it * 256;                 // 0..1023
        int r = j >> 4, d0 = (j & 15) * 4;
        size_t g = (size_t)(c * CHUNK + r) * DM + h * 64 + d0;
        f32x4 q = *(const f32x4*)(Qb + g);
        f32x4 k = *(const f32x4*)(Kb + g);
        f32x4 v = *(const f32x4*)(Vb + g);
        Qt[d0 + 0][r] = q.x; Qt[d0 + 1][r] = q.y; Qt[d0 + 2][r] = q.z; Qt[d0 + 3][r] = q.w;
        Kt[d0 + 0][r] = k.x; Kt[d0 + 1][r] = k.y; Kt[d0 + 2][r] = k.z; Kt[d0 + 3][r] = k.w;
        *(f32x4*)(&Vs[r][d0]) = v;
        *(f32x4*)(&Ms[r][d0]) = *(const f32x4*)(ms_src + (size_t)j * 4);
    }
    if (tid < 64) KSs[tid] = KSC[(size_t)(c * NH + h) * 64 + tid];
    __syncthreads();

    const int si = tid >> 4, ti = tid & 15;
    const int s0 = si * 4, t0 = ti * 4;         // t0 doubles as e0

    // ---- Phase A: inter-chunk O = Q @ State, den = Q . KSprefix ----
    f32x4 accO0 = {}, accO1 = {}, accO2 = {}, accO3 = {};
    f32x4 den = {};
    #pragma unroll 8
    for (int d = 0; d < 64; ++d) {
        f32x4 qv = *(const f32x4*)(&Qt[d][s0]);
        f32x4 mv = *(const f32x4*)(&Ms[d][t0]);
        float ks = KSs[d];
        fma4(accO0, qv.x, mv); fma4(accO1, qv.y, mv);
        fma4(accO2, qv.z, mv); fma4(accO3, qv.w, mv);
        fma4(den, ks, qv);
    }

    // ---- Phase B: S = Q K^T, causal, staged transposed ----
    f32x4 p0 = {}, p1 = {}, p2 = {}, p3 = {};   // p_r = S[s0+r][t0:t0+4]
    if (ti <= si) {
        #pragma unroll 8
        for (int d = 0; d < 64; ++d) {
            f32x4 qv = *(const f32x4*)(&Qt[d][s0]);
            f32x4 kv = *(const f32x4*)(&Kt[d][t0]);
            fma4(p0, qv.x, kv); fma4(p1, qv.y, kv);
            fma4(p2, qv.z, kv); fma4(p3, qv.w, kv);
        }
        if (ti == si) {                          // diagonal tile: keep t<=r
            p0.y = 0.0f; p0.z = 0.0f; p0.w = 0.0f;
            p1.z = 0.0f; p1.w = 0.0f;
            p2.w = 0.0f;
        }
    }
    St[t0 + 0][s0 + 0] = p0.x; St[t0 + 1][s0 + 0] = p0.y;
    St[t0 + 2][s0 + 0] = p0.z; St[t0 + 3][s0 + 0] = p0.w;
    St[t0 + 0][s0 + 1] = p1.x; St[t0 + 1][s0 + 1] = p1.y;
    St[t0 + 2][s0 + 1] = p1.z; St[t0 + 3][s0 + 1] = p1.w;
    St[t0 + 0][s0 + 2] = p2.x; St[t0 + 1][s0 + 2] = p2.y;
    St[t0 + 2][s0 + 2] = p2.z; St[t0 + 3][s0 + 2] = p2.w;
    St[t0 + 0][s0 + 3] = p3.x; St[t0 + 1][s0 + 3] = p3.y;
    St[t0 + 2][s0 + 3] = p3.z; St[t0 + 3][s0 + 3] = p3.w;
    __syncthreads();

    // ---- Phase C: O += S @ V ; den += rowsum(S) ----
    const int tmax = s0 + 4;                     // exclusive; St zero above diag
    #pragma unroll 4
    for (int t2 = 0; t2 < tmax; ++t2) {
        f32x4 sv = *(const f32x4*)(&St[t2][s0]);
        f32x4 vv = *(const f32x4*)(&Vs[t2][t0]);
        fma4(accO0, sv.x, vv); fma4(accO1, sv.y, vv);
        fma4(accO2, sv.z, vv); fma4(accO3, sv.w, vv);
        den += sv;
    }

    // ---- epilogue: z = 1/(den+eps), bf16 out ----
    short* op = Ab + (size_t)(c * CHUNK + s0) * DM + h * 64 + t0;
    {
        float z = 1.0f / (den.x + 1e-6f);
        short4 o; o.x = f2bf(accO0.x * z); o.y = f2bf(accO0.y * z);
        o.z = f2bf(accO0.z * z); o.w = f2bf(accO0.w * z);
        *reinterpret_cast<short4*>(op) = o;
    }
    {
        float z = 1.0f / (den.y + 1e-6f);
        short4 o; o.x = f2bf(accO1.x * z); o.y = f2bf(accO1.y * z);
        o.z = f2bf(accO1.z * z); o.w = f2bf(accO1.w * z);
        *reinterpret_cast<short4*>(op + DM) = o;
    }
    {
        float z = 1.0f / (den.z + 1e-6f);
        short4 o; o.x = f2bf(accO2.x * z); o.y = f2bf(accO2.y * z);
        o.z = f2bf(accO2.z * z); o.w = f2bf(accO2.w * z);
        *reinterpret_cast<short4*>(op + 2 * DM) = o;
    }
    {
        float z = 1.0f / (den.w + 1e-6f);
        short4 o; o.x = f2bf(accO3.x * z); o.y = f2bf(accO3.y * z);
        o.z = f2bf(accO3.z * z); o.w = f2bf(accO3.w * z);
        *reinterpret_cast<short4*>(op + 3 * DM) = o;
    }
}

// ---------------- layernorm (fp32 out + optional bf16 mirror) ----------------
__device__ __forceinline__ float block_reduce_sum(float v, float* smem)
{
    #pragma unroll
    for (int o = 32; o > 0; o >>= 1) v += __shfl_down(v, o, 64);
    int w = threadIdx.x >> 6;
    if ((threadIdx.x & 63) == 0) smem[w] = v;
    __syncthreads();
    v = smem[0] + smem[1] + smem[2] + smem[3];
    __syncthreads();
    return v;
}

__global__ __launch_bounds__(256) void ln_kernel(
    const float* __restrict__ X, const float* __restrict__ g,
    const float* __restrict__ b, float* __restrict__ O, short* __restrict__ Ob)
{
    __shared__ float red[4];
    const int row = blockIdx.x;
    const float* x = X + (size_t)row * DM;
    const int t = threadIdx.x;
    float v0 = x[t], v1 = x[t + 256];
    float mean = block_reduce_sum(v0 + v1, red) * (1.0f / 512.0f);
    float d0 = v0 - mean, d1 = v1 - mean;
    float var = block_reduce_sum(d0 * d0 + d1 * d1, red) * (1.0f / 512.0f);
    float rs = 1.0f / sqrtf(var + 1e-5f);
    float o0 = d0 * rs * g[t] + b[t];
    float o1 = d1 * rs * g[t + 256] + b[t + 256];
    O[(size_t)row * DM + t]       = o0;
    O[(size_t)row * DM + t + 256] = o1;
    if (Ob) {
        Ob[(size_t)row * DM + t]       = f2bf(o0);
        Ob[(size_t)row * DM + t + 256] = f2bf(o1);
    }
}

// ---------------- emotion head: [1024,512] @ [512,8] + b ----------------
__global__ __launch_bounds__(256) void proj_emo_kernel(
    const float* __restrict__ HF, const float* __restrict__ pw,
    const float* __restrict__ pb, float* __restrict__ out)
{
    int idx = blockIdx.x * 256 + threadIdx.x;
    int r = idx >> 3, e = idx & 7;
    float acc = pb[e];
    const float* h = HF + (size_t)r * DM;
    for (int d = 0; d < DM; ++d) acc += h[d] * pw[d * 8 + e];
    out[idx] = acc;
}

// ---------------------------------------------------------------------------
extern "C" void kernel_launch(void* const* d_in, const int* in_sizes, int n_in,
                              void* d_out, int out_size, void* d_ws, size_t ws_size,
                              hipStream_t stream)
{
    const int*   x    = (const int*)d_in[0];
    const float* e0   = (const float*)d_in[1];
    const float* e1   = (const float*)d_in[2];
    const float* e2   = (const float*)d_in[3];
    const float* e3   = (const float*)d_in[4];
    const float* e4   = (const float*)d_in[5];
    const float* e5   = (const float*)d_in[6];
    const float* in_w = (const float*)d_in[7];
    const float* in_b = (const float*)d_in[8];
    const float* wq   = (const float*)d_in[9];
    const float* bq   = (const float*)d_in[10];
    const float* wk   = (const float*)d_in[11];
    const float* bk   = (const float*)d_in[12];
    const float* wv   = (const float*)d_in[13];
    const float* bv   = (const float*)d_in[14];
    const float* wo   = (const float*)d_in[15];
    const float* bo   = (const float*)d_in[16];
    const float* g1   = (const float*)d_in[17];
    const float* be1  = (const float*)d_in[18];
    const float* w1   = (const float*)d_in[19];
    const float* b1   = (const float*)d_in[20];
    const float* w2   = (const float*)d_in[21];
    const float* b2   = (const float*)d_in[22];
    const float* g2   = (const float*)d_in[23];
    const float* be2  = (const float*)d_in[24];
    const float* gf   = (const float*)d_in[25];
    const float* bfin = (const float*)d_in[26];
    const float* pw   = (const float*)d_in[27];
    const float* pb   = (const float*)d_in[28];
    float* outp = (float*)d_out;

    // ---- workspace layout (unchanged from R10) ----
    float* ws = (float*)d_ws;
    float* H    = ws;                  // 1024x512 f32
    float* Y    = ws + 524288;         // 1024x512 f32
    float* Qb   = ws + 1048576;
    float* Kb   = ws + 1572864;
    float* Vb   = ws + 2097152;
    float* KVC  = ws + 2621440;        // 16*8*4096 = 524288
    float* KSC  = ws + 3145728;        // 8192 (f32 end: 3153920 floats)
    short* sb   = (short*)(ws + 3153920);
    short* Hb   = sb;                  // 1024x512
    short* Ab   = sb + 524288;         // 1024x512
    short* FFb  = sb + 1048576;        // 1024x2048
    short* EMBb = FFb;                 // 1024x768 (alias: dead before ffn1)
    // bf16 W^T arena [N][K]
    short* inT  = sb + 3145728;        // [512][768]
    short* qT   = inT + 393216;        // [12][512][512]
    short* kT   = qT + 3145728;
    short* vT   = kT + 3145728;
    short* oT   = vT + 3145728;
    short* w1T  = oT + 3145728;        // [12][2048][512]
    short* w2T  = w1T + 12582912;      // [12][512][2048]  (total ~90.8 MB)

    const dim3 blk256(256);

    // ---- weight transpose+convert ----
    transpose_w<<<dim3(8, 12, 1),  blk256, 0, stream>>>(in_w, inT, 768, DM);
    transpose_w<<<dim3(8, 8, 12),  blk256, 0, stream>>>(wq, qT, DM, DM);
    transpose_w<<<dim3(8, 8, 12),  blk256, 0, stream>>>(wk, kT, DM, DM);
    transpose_w<<<dim3(8, 8, 12),  blk256, 0, stream>>>(wv, vT, DM, DM);
    transpose_w<<<dim3(8, 8, 12),  blk256, 0, stream>>>(wo, oT, DM, DM);
    transpose_w<<<dim3(32, 8, 12), blk256, 0, stream>>>(w1, w1T, DM, DFF);
    transpose_w<<<dim3(8, 32, 12), blk256, 0, stream>>>(w2, w2T, DFF, DM);

    embed_kernel<<<S_LEN, blk256, 0, stream>>>(x, e0, e1, e2, e3, e4, e5, EMBb);
    // in-proj: EMBb @ in_w + in_b + PE -> H (f32) and Hb (bf16)
    gemm64<<<dim3(8, 16), blk256, 0, stream>>>(EMBb, inT, in_b, nullptr,
                                               H, Hb, DM, 768, ACT_NONE, 1);

    for (int l = 0; l < NLAYER; ++l) {
        const short* qT_l = qT + (size_t)l * DM * DM;
        const short* kT_l = kT + (size_t)l * DM * DM;
        const short* vT_l = vT + (size_t)l * DM * DM;
        const short* oT_l = oT + (size_t)l * DM * DM;
        const short* w1T_l = w1T + (size_t)l * DM * DFF;
        const short* w2T_l = w2T + (size_t)l * DM * DFF;
        const float* bq_l = bq + l * DM;  const float* bk_l = bk + l * DM;
        const float* bv_l = bv + l * DM;  const float* bo_l = bo + l * DM;
        const float* b1_l = b1 + l * DFF; const float* b2_l = b2 + l * DM;

        qkv64<<<dim3(24, 16), blk256, 0, stream>>>(Hb, qT_l, kT_l, vT_l,
                                                   bq_l, bk_l, bv_l, Qb, Kb, Vb);

        chunk_stats_kernel<<<NCH * NH, blk256, 0, stream>>>(Kb, Vb, KVC, KSC);
        scan_kv_kernel<<<32, blk256, 0, stream>>>(KVC, KSC);
        attn_out_kernel<<<NCH * NH, blk256, 0, stream>>>(Qb, Kb, Vb, KVC, KSC, Ab);

        // wo: Ab @ wo + bo + resid(H) -> Y (f32); then LN -> H, Hb
        gemm64<<<dim3(8, 16), blk256, 0, stream>>>(Ab, oT_l, bo_l, H,
                                                   Y, nullptr, DM, DM, ACT_NONE, 0);
        ln_kernel<<<S_LEN, blk256, 0, stream>>>(Y, g1 + l * DM, be1 + l * DM, H, Hb);

        // ffn1: Hb @ w1 + b1, GELU -> FFb (bf16)
        gemm64<<<dim3(32, 16), blk256, 0, stream>>>(Hb, w1T_l, b1_l, nullptr,
                                                    nullptr, FFb, DFF, DM, ACT_GELU, 0);
        // ffn2: FFb @ w2 + b2 + resid(H) -> Y (f32); then LN -> H, Hb
        gemm64<<<dim3(8, 16), blk256, 0, stream>>>(FFb, w2T_l, b2_l, H,
                                                   Y, nullptr, DM, DFF, ACT_NONE, 0);
        ln_kernel<<<S_LEN, blk256, 0, stream>>>(Y, g2 + l * DM, be2 + l * DM, H, Hb);
    }

    // final norm -> d_out (f32 h), then emotion head
    ln_kernel<<<S_LEN, blk256, 0, stream>>>(H, gf, bfin, outp, nullptr);
    proj_emo_kernel<<<8192 / 256, blk256, 0, stream>>>(outp, pw, pb, outp + 524288);
}